// Round 6
// baseline (158.093 us; speedup 1.0000x reference)
//
#include <hip/hip_runtime.h>
#include <math.h>

#define OUT_DIM 8192
#define C_DIM   512
#define B_DIM   16
#define HW      196

typedef __attribute__((ext_vector_type(8))) short bf16x8;
typedef __attribute__((ext_vector_type(4))) float f32x4;

// Packed fragment-native layout, per plane (hi or lo):
//   idx(b, rb, kb, lk, r, e) = (((b*32 + rb)*7 + kb)*4 + lk)*128 + r*8 + e
// A wave's 16x32 fragment at (rb,kb) = contiguous 1KB; lane l reads 16B at l*16.

// ---------------------------------------------------------------------------
// K1 prep: [0,1024) sketch extraction (+ zero per-batch counters);
//          [1024,1536) pack x -> fragment-native bf16 hi/lo planes.
// ---------------------------------------------------------------------------
__global__ __launch_bounds__(256) void prep(
    const float* __restrict__ x,
    const float* __restrict__ S1, const float* __restrict__ S2,
    int* __restrict__ h1, float* __restrict__ s1,
    int* __restrict__ h2, float* __restrict__ s2,
    unsigned short* __restrict__ PH, unsigned short* __restrict__ PLo,
    int* __restrict__ cnt)
{
    const int bid = blockIdx.x;
    const int t = threadIdx.x;

    if (bid < 1024) {
        int row = bid & 511;
        const float* S = (bid < 512) ? S1 : S2;
        int* h = (bid < 512) ? h1 : h2;
        float* s = (bid < 512) ? s1 : s2;
        const float4* p = (const float4*)(S + (size_t)row * OUT_DIM);
#pragma unroll
        for (int m = 0; m < 8; ++m) {
            int q = t + m * 256;
            float4 v = p[q];
            int base = q * 4;
            if (v.x != 0.f) { h[row] = base + 0; s[row] = v.x; }
            if (v.y != 0.f) { h[row] = base + 1; s[row] = v.y; }
            if (v.z != 0.f) { h[row] = base + 2; s[row] = v.z; }
            if (v.w != 0.f) { h[row] = base + 3; s[row] = v.w; }
        }
        if (bid == 0 && t < B_DIM) cnt[t] = 0;
        return;
    }

    // pack: one block per (b, rb) = 16 rows of one batch
    const int u = bid - 1024;             // 0..511
    const int b = u >> 5, rb = u & 31;
    __shared__ float xs[16 * HW];
    const float* src = x + ((size_t)b * C_DIM + rb * 16) * HW;
#pragma unroll
    for (int i = 0; i < 13; ++i) {
        int idx = t + i * 256;
        if (idx < 16 * HW) xs[idx] = src[idx];
    }
    __syncthreads();

    const int r = t & 15, u0 = t >> 4;
#pragma unroll
    for (int p = 0; p < 2; ++p) {
        int unit = u0 + p * 16;           // 0..27
        if (unit < 28) {
            bf16x8 hv, lv;
#pragma unroll
            for (int e = 0; e < 8; ++e) {
                int k = unit * 8 + e;
                float v = (k < HW) ? xs[r * HW + k] : 0.f;
                unsigned int uv = __float_as_uint(v);
                unsigned short hi = (unsigned short)(uv >> 16);
                float hif = __uint_as_float(((unsigned int)hi) << 16);
                hv[e] = (short)hi;
                lv[e] = (short)(__float_as_uint(v - hif) >> 16);
            }
            int kb = unit >> 2, lk = unit & 3;
            size_t base = ((((size_t)b * 32 + rb) * 7 + kb) * 4 + lk) * 128 + r * 8;
            *(bf16x8*)(PH + base) = hv;
            *(bf16x8*)(PLo + base) = lv;
        }
    }
}

// ---------------------------------------------------------------------------
// K2: fused Gram-MFMA + scatter + (last-block) finalize.
// 256 blocks x 512 thr (8 waves = 2/SIMD). Block (b, 128x128 tile).
// Wave grid 2x4: 64x32 sub-tile, acc[4][2]; fragments loaded directly from
// L2-resident packed planes, register double-buffered, no K-loop barriers.
// Scatter into LDS bins -> per-block partial slab. Last block of each batch
// (XCD-local counter) reduces 16 slabs, signed-sqrt, L2-norm, writes out.
// ---------------------------------------------------------------------------
__global__ __launch_bounds__(512) void gram_fused(
    const unsigned short* __restrict__ PH, const unsigned short* __restrict__ PLo,
    const int* __restrict__ h1, const float* __restrict__ s1,
    const int* __restrict__ h2, const float* __restrict__ s2,
    float* __restrict__ partials, int* __restrict__ cnt,
    float* __restrict__ out)
{
    __shared__ float bins[OUT_DIM];       // 32 KB
    __shared__ float red[8];
    __shared__ int lastflag;

    const int bid = blockIdx.x;
    const int xcd = bid & 7;
    const int idx = bid >> 3;             // 0..31
    const int b   = xcd + 8 * (idx & 1);  // all 16 tiles of b on one XCD
    const int tile = idx >> 1;            // 0..15
    const int c1b = (tile >> 2) * 128, c2b = (tile & 3) * 128;

    const int t = threadIdx.x;
    const int l = t & 63, w = t >> 6;
    const int wr = w >> 2, wc = w & 3;    // 2x4 wave grid: 64x32 per wave

    for (int mm = t; mm < OUT_DIM; mm += 512) bins[mm] = 0.f;

    const size_t arb0 = ((size_t)b * 32 + (c1b >> 4) + wr * 4) * 7;  // +m*7
    const size_t brb0 = ((size_t)b * 32 + (c2b >> 4) + wc * 2) * 7;  // +n*7
    const int loff = l * 8;

#define FRAG(P, rbase, m, kb) (*(const bf16x8*)((P) + ((rbase) + (size_t)(m) * 7 + (kb)) * 512 + loff))

    f32x4 acc[4][2];
#pragma unroll
    for (int m = 0; m < 4; ++m)
#pragma unroll
        for (int n = 0; n < 2; ++n) acc[m][n] = (f32x4){0.f, 0.f, 0.f, 0.f};

    bf16x8 ah[2][4], al[2][4], bh[2][2], bl[2][2];
#pragma unroll
    for (int m = 0; m < 4; ++m) {
        ah[0][m] = FRAG(PH,  arb0, m, 0);
        al[0][m] = FRAG(PLo, arb0, m, 0);
    }
#pragma unroll
    for (int n = 0; n < 2; ++n) {
        bh[0][n] = FRAG(PH,  brb0, n, 0);
        bl[0][n] = FRAG(PLo, brb0, n, 0);
    }

#pragma unroll
    for (int kb = 0; kb < 7; ++kb) {
        const int cur = kb & 1, nxt = cur ^ 1;
        if (kb < 6) {
#pragma unroll
            for (int m = 0; m < 4; ++m) {
                ah[nxt][m] = FRAG(PH,  arb0, m, kb + 1);
                al[nxt][m] = FRAG(PLo, arb0, m, kb + 1);
            }
#pragma unroll
            for (int n = 0; n < 2; ++n) {
                bh[nxt][n] = FRAG(PH,  brb0, n, kb + 1);
                bl[nxt][n] = FRAG(PLo, brb0, n, kb + 1);
            }
        }
#pragma unroll
        for (int m = 0; m < 4; ++m)
#pragma unroll
            for (int n = 0; n < 2; ++n) {
                acc[m][n] = __builtin_amdgcn_mfma_f32_16x16x32_bf16(ah[cur][m], bh[cur][n], acc[m][n], 0, 0, 0);
                acc[m][n] = __builtin_amdgcn_mfma_f32_16x16x32_bf16(ah[cur][m], bl[cur][n], acc[m][n], 0, 0, 0);
                acc[m][n] = __builtin_amdgcn_mfma_f32_16x16x32_bf16(al[cur][m], bh[cur][n], acc[m][n], 0, 0, 0);
            }
    }
#undef FRAG

    // C/D layout (verified R3-R5): c2 = col = lane&15, c1 = row = (lane>>4)*4 + reg
    const int lrow = l & 15, lk = l >> 4;
    int   hh1[4][4]; float sv1[4][4];
    int   hh2[2];    float sv2[2];
#pragma unroll
    for (int m = 0; m < 4; ++m)
#pragma unroll
        for (int r = 0; r < 4; ++r) {
            int c1 = c1b + wr * 64 + m * 16 + lk * 4 + r;
            hh1[m][r] = h1[c1]; sv1[m][r] = s1[c1];
        }
#pragma unroll
    for (int n = 0; n < 2; ++n) {
        int c2 = c2b + wc * 32 + n * 16 + lrow;
        hh2[n] = h2[c2]; sv2[n] = s2[c2];
    }

    __syncthreads();                      // bins zeroed; all frag loads done
#pragma unroll
    for (int m = 0; m < 4; ++m)
#pragma unroll
        for (int n = 0; n < 2; ++n)
#pragma unroll
            for (int r = 0; r < 4; ++r) {
                int bin = (hh1[m][r] + hh2[n]) & (OUT_DIM - 1);
                atomicAdd(&bins[bin], acc[m][n][r] * sv1[m][r] * sv2[n]);
            }
    __syncthreads();

    float* outp = partials + (size_t)(b * 16 + tile) * OUT_DIM;
    for (int mm = t; mm < OUT_DIM; mm += 512) outp[mm] = bins[mm];

    // -------- last-block finalize (per batch; same-XCD counter) --------
    __threadfence();                      // make slab visible (release)
    __syncthreads();                      // all threads' stores fenced
    if (t == 0) lastflag = (atomicAdd(&cnt[b], 1) == 15);
    __syncthreads();
    if (!lastflag) return;
    __threadfence();                      // acquire other blocks' slabs

    const float4* p4 = (const float4*)(partials + (size_t)b * 16 * OUT_DIM);
    float4 va[4];
    float sq = 0.f;
#pragma unroll
    for (int i = 0; i < 4; ++i) {
        int q = t + i * 512;              // float4 unit, 2048 per slab
        float4 s = make_float4(0.f, 0.f, 0.f, 0.f);
#pragma unroll
        for (int tl = 0; tl < 16; ++tl) {
            float4 v = p4[tl * 2048 + q];
            s.x += v.x; s.y += v.y; s.z += v.z; s.w += v.w;
        }
        float comp[4] = {s.x, s.y, s.z, s.w};
#pragma unroll
        for (int e = 0; e < 4; ++e) {
            float a = comp[e] * (float)OUT_DIM;
            float sg = (a > 0.f) ? 1.f : ((a < 0.f) ? -1.f : 0.f);
            comp[e] = sg * sqrtf(fabsf(a) + 1e-5f);
            sq += comp[e] * comp[e];
        }
        va[i] = make_float4(comp[0], comp[1], comp[2], comp[3]);
    }
#pragma unroll
    for (int off = 32; off; off >>= 1) sq += __shfl_down(sq, off, 64);
    if (l == 0) red[w] = sq;
    __syncthreads();
    float tot = 0.f;
#pragma unroll
    for (int i = 0; i < 8; ++i) tot += red[i];
    float inv = 1.f / fmaxf(sqrtf(tot), 1e-12f);

    float4* o4 = (float4*)(out + (size_t)b * OUT_DIM);
#pragma unroll
    for (int i = 0; i < 4; ++i) {
        int q = t + i * 512;
        o4[q] = make_float4(va[i].x * inv, va[i].y * inv, va[i].z * inv, va[i].w * inv);
    }
}

// ---------------------------------------------------------------------------
extern "C" void kernel_launch(void* const* d_in, const int* in_sizes, int n_in,
                              void* d_out, int out_size, void* d_ws, size_t ws_size,
                              hipStream_t stream) {
    const float* x   = (const float*)d_in[0];
    const float* sk1 = (const float*)d_in[1];
    const float* sk2 = (const float*)d_in[2];

    char* ws = (char*)d_ws;
    int*   h1 = (int*)(ws);                              //       0 + 2048
    float* s1 = (float*)(ws + 2048);                     //    2048 + 2048
    int*   h2 = (int*)(ws + 4096);                       //    4096 + 2048
    float* s2 = (float*)(ws + 6144);                     //    6144 + 2048
    int*   cnt = (int*)(ws + 8192);                      //    8192 + 256
    float* partials = (float*)(ws + 8448);               // [256][8192] f32 = 8388608
    unsigned short* PH  = (unsigned short*)(ws + 8397056);   // 7340032 B
    unsigned short* PLo = (unsigned short*)(ws + 15737088);  // 7340032 B -> 23077120 total

    prep<<<1536, 256, 0, stream>>>(x, sk1, sk2, h1, s1, h2, s2, PH, PLo, cnt);
    gram_fused<<<256, 512, 0, stream>>>(PH, PLo, h1, s1, h2, s2, partials, cnt, (float*)d_out);
}

// Round 7
// 140.700 us; speedup vs baseline: 1.1236x; 1.1236x over previous
//
#include <hip/hip_runtime.h>
#include <math.h>

#define OUT_DIM 8192
#define C_DIM   512
#define B_DIM   16
#define HW      196

typedef __attribute__((ext_vector_type(8))) short bf16x8;
typedef __attribute__((ext_vector_type(4))) float f32x4;

// Packed fragment-native layout, per plane (hi or lo), 8 kb-chunks (kb7 = zeros):
//   idx(b, rb, kb, lk, r, e) = ((((b*32 + rb)*8 + kb)*4 + lk)*128 + r*8 + e
// A wave's 16x32 fragment at (rb,kb) = contiguous 1KB; lane l reads 16B at l*16.
// Plane size: 16*32*8*512 ushorts = 4 MB.

// ---------------------------------------------------------------------------
// K1 prep: [0,1024) sketch extraction; [1024,1536) pack x -> fragment planes.
// ---------------------------------------------------------------------------
__global__ __launch_bounds__(256) void prep(
    const float* __restrict__ x,
    const float* __restrict__ S1, const float* __restrict__ S2,
    int* __restrict__ h1, float* __restrict__ s1,
    int* __restrict__ h2, float* __restrict__ s2,
    unsigned short* __restrict__ PH, unsigned short* __restrict__ PLo)
{
    const int bid = blockIdx.x;
    const int t = threadIdx.x;

    if (bid < 1024) {
        int row = bid & 511;
        const float* S = (bid < 512) ? S1 : S2;
        int* h = (bid < 512) ? h1 : h2;
        float* s = (bid < 512) ? s1 : s2;
        const float4* p = (const float4*)(S + (size_t)row * OUT_DIM);
#pragma unroll
        for (int m = 0; m < 8; ++m) {
            int q = t + m * 256;
            float4 v = p[q];
            int base = q * 4;
            if (v.x != 0.f) { h[row] = base + 0; s[row] = v.x; }
            if (v.y != 0.f) { h[row] = base + 1; s[row] = v.y; }
            if (v.z != 0.f) { h[row] = base + 2; s[row] = v.z; }
            if (v.w != 0.f) { h[row] = base + 3; s[row] = v.w; }
        }
        return;
    }

    // pack: one block per (b, rb) = 16 rows of one batch
    const int u = bid - 1024;             // 0..511
    const int b = u >> 5, rb = u & 31;
    __shared__ float xs[16 * HW];
    const float* src = x + ((size_t)b * C_DIM + rb * 16) * HW;
#pragma unroll
    for (int i = 0; i < 13; ++i) {
        int idx = t + i * 256;
        if (idx < 16 * HW) xs[idx] = src[idx];
    }
    __syncthreads();

    const int r = t & 15, u0 = t >> 4;
#pragma unroll
    for (int p = 0; p < 2; ++p) {
        int unit = u0 + p * 16;           // 0..31 (units 28..31 -> zeros, kb7 pad)
        bf16x8 hv, lv;
#pragma unroll
        for (int e = 0; e < 8; ++e) {
            int k = unit * 8 + e;
            float v = (k < HW) ? xs[r * HW + k] : 0.f;
            unsigned int uv = __float_as_uint(v);
            unsigned short hi = (unsigned short)(uv >> 16);
            float hif = __uint_as_float(((unsigned int)hi) << 16);
            hv[e] = (short)hi;
            lv[e] = (short)(__float_as_uint(v - hif) >> 16);
        }
        int kb = unit >> 2, lk = unit & 3;
        size_t base = ((((size_t)b * 32 + rb) * 8 + kb) * 4 + lk) * 128 + r * 8;
        *(bf16x8*)(PH + base) = hv;
        *(bf16x8*)(PLo + base) = lv;
    }
}

// ---------------------------------------------------------------------------
// K2: Gram via MFMA, fragments direct from L2-resident packed planes.
// 256 blocks x 512 thr (8 waves = 2/SIMD; launch_bounds(512,2) -> 256-reg cap,
// NO spills). Block (b, 128x128 tile). Wave w: K-half = w>>2 (kb 0-3 / 4-7),
// quadrant (wr,wc) = ((w>>1)&1, w&1), 64x64 tile, acc[4][4].
// Register double-buffer over 4 kb, no barriers in K-loop. Both K-halves
// scatter into shared LDS bins (atomics sum them). Deterministic slab out.
// XCD swizzle: bid&7 = XCD, 2 batches/XCD -> packed planes (1 MB) L2-resident.
// ---------------------------------------------------------------------------
__global__ __launch_bounds__(512, 2) void gram_mfma(
    const unsigned short* __restrict__ PH, const unsigned short* __restrict__ PLo,
    const int* __restrict__ h1, const float* __restrict__ s1,
    const int* __restrict__ h2, const float* __restrict__ s2,
    float* __restrict__ partials)
{
    __shared__ float bins[OUT_DIM];       // 32 KB

    const int bid = blockIdx.x;
    const int xcd = bid & 7;
    const int idx = bid >> 3;             // 0..31
    const int b   = xcd + 8 * (idx & 1);
    const int tile = idx >> 1;            // 0..15
    const int c1b = (tile >> 2) * 128, c2b = (tile & 3) * 128;

    const int t = threadIdx.x;
    const int l = t & 63, w = t >> 6;
    const int half = w >> 2;              // K-half: kb0 = half*4
    const int wr = (w >> 1) & 1, wc = w & 1;

    for (int mm = t; mm < OUT_DIM; mm += 512) bins[mm] = 0.f;

    // frag(rb, kb) base: ((b*32+rb)*8 + kb)*512 + l*8
    const int arb = b * 32 + (c1b >> 4) + wr * 4;   // + m
    const int brb = b * 32 + (c2b >> 4) + wc * 4;   // + n
    const int loff = l * 8;
    const int kb0 = half * 4;

#define FRAG(P, rb, kb) (*(const bf16x8*)((P) + ((size_t)((rb) * 8 + (kb)) * 512) + loff))

    f32x4 acc[4][4];
#pragma unroll
    for (int m = 0; m < 4; ++m)
#pragma unroll
        for (int n = 0; n < 4; ++n) acc[m][n] = (f32x4){0.f, 0.f, 0.f, 0.f};

    bf16x8 ah[2][4], al[2][4], bh[2][4], bl[2][4];
#pragma unroll
    for (int m = 0; m < 4; ++m) {
        ah[0][m] = FRAG(PH,  arb + m, kb0);
        al[0][m] = FRAG(PLo, arb + m, kb0);
        bh[0][m] = FRAG(PH,  brb + m, kb0);
        bl[0][m] = FRAG(PLo, brb + m, kb0);
    }

#pragma unroll
    for (int i = 0; i < 4; ++i) {
        const int cur = i & 1, nxt = cur ^ 1;
        if (i < 3) {
            const int kn = kb0 + i + 1;
#pragma unroll
            for (int m = 0; m < 4; ++m) {
                ah[nxt][m] = FRAG(PH,  arb + m, kn);
                al[nxt][m] = FRAG(PLo, arb + m, kn);
                bh[nxt][m] = FRAG(PH,  brb + m, kn);
                bl[nxt][m] = FRAG(PLo, brb + m, kn);
            }
        }
#pragma unroll
        for (int m = 0; m < 4; ++m)
#pragma unroll
            for (int n = 0; n < 4; ++n) {
                acc[m][n] = __builtin_amdgcn_mfma_f32_16x16x32_bf16(ah[cur][m], bh[cur][n], acc[m][n], 0, 0, 0);
                acc[m][n] = __builtin_amdgcn_mfma_f32_16x16x32_bf16(ah[cur][m], bl[cur][n], acc[m][n], 0, 0, 0);
                acc[m][n] = __builtin_amdgcn_mfma_f32_16x16x32_bf16(al[cur][m], bh[cur][n], acc[m][n], 0, 0, 0);
            }
    }
#undef FRAG

    // C/D layout (verified R3-R6): c2 = col = lane&15, c1 = row = (lane>>4)*4 + reg
    const int lrow = l & 15, lk = l >> 4;
    int   hh1[4][4]; float sv1[4][4];
    int   hh2[4];    float sv2[4];
#pragma unroll
    for (int m = 0; m < 4; ++m)
#pragma unroll
        for (int r = 0; r < 4; ++r) {
            int c1 = c1b + wr * 64 + m * 16 + lk * 4 + r;
            hh1[m][r] = h1[c1]; sv1[m][r] = s1[c1];
        }
#pragma unroll
    for (int n = 0; n < 4; ++n) {
        int c2 = c2b + wc * 64 + n * 16 + lrow;
        hh2[n] = h2[c2]; sv2[n] = s2[c2];
    }

    __syncthreads();                      // bins zeroed; all frag loads done
#pragma unroll
    for (int m = 0; m < 4; ++m)
#pragma unroll
        for (int n = 0; n < 4; ++n)
#pragma unroll
            for (int r = 0; r < 4; ++r) {
                int bin = (hh1[m][r] + hh2[n]) & (OUT_DIM - 1);
                atomicAdd(&bins[bin], acc[m][n][r] * sv1[m][r] * sv2[n]);
            }
    __syncthreads();

    float* outp = partials + (size_t)(b * 16 + tile) * OUT_DIM;
    for (int mm = t; mm < OUT_DIM; mm += 512) outp[mm] = bins[mm];
}

// ---------------------------------------------------------------------------
// K3 fin: one block per batch (1024 thr, 16 waves). Block b lands on XCD b&7
// (same as gram's slabs -> L2-local). Reduce 16 slabs, *8192, signed sqrt,
// block-reduce L2 norm, normalize, write out.
// ---------------------------------------------------------------------------
__global__ __launch_bounds__(1024) void fin(
    const float* __restrict__ partials, float* __restrict__ out)
{
    const int b = blockIdx.x, t = threadIdx.x;
    const float* pb = partials + (size_t)b * 16 * OUT_DIM;
    float v[8];
    float sq = 0.f;
#pragma unroll
    for (int i = 0; i < 8; ++i) {
        int k = t + i * 1024;
        float a = 0.f;
#pragma unroll
        for (int tl = 0; tl < 16; ++tl)
            a += pb[tl * OUT_DIM + k];
        a *= (float)OUT_DIM;
        float sg = (a > 0.f) ? 1.f : ((a < 0.f) ? -1.f : 0.f);
        v[i] = sg * sqrtf(fabsf(a) + 1e-5f);
        sq += fabsf(a) + 1e-5f;           // = v[i]^2
    }
#pragma unroll
    for (int off = 32; off; off >>= 1) sq += __shfl_down(sq, off, 64);
    __shared__ float red[16];
    if ((t & 63) == 0) red[t >> 6] = sq;
    __syncthreads();
    float tot = 0.f;
#pragma unroll
    for (int i = 0; i < 16; ++i) tot += red[i];
    float inv = 1.f / fmaxf(sqrtf(tot), 1e-12f);
#pragma unroll
    for (int i = 0; i < 8; ++i)
        out[(size_t)b * OUT_DIM + t + i * 1024] = v[i] * inv;
}

// ---------------------------------------------------------------------------
extern "C" void kernel_launch(void* const* d_in, const int* in_sizes, int n_in,
                              void* d_out, int out_size, void* d_ws, size_t ws_size,
                              hipStream_t stream) {
    const float* x   = (const float*)d_in[0];
    const float* sk1 = (const float*)d_in[1];
    const float* sk2 = (const float*)d_in[2];

    char* ws = (char*)d_ws;
    int*   h1 = (int*)(ws);                              //       0 + 2048
    float* s1 = (float*)(ws + 2048);                     //    2048 + 2048
    int*   h2 = (int*)(ws + 4096);                       //    4096 + 2048
    float* s2 = (float*)(ws + 6144);                     //    6144 + 2048
    float* partials = (float*)(ws + 8192);               // [256][8192] f32 = 8388608
    unsigned short* PH  = (unsigned short*)(ws + 8396800);   // 4 MB (16*32*8*512 u16)
    unsigned short* PLo = (unsigned short*)(ws + 12591104);  // 4 MB -> 16785408 total

    prep<<<1536, 256, 0, stream>>>(x, sk1, sk2, h1, s1, h2, s2, PH, PLo);
    gram_mfma<<<256, 512, 0, stream>>>(PH, PLo, h1, s1, h2, s2, partials);
    fin<<<B_DIM, 1024, 0, stream>>>(partials, (float*)d_out);
}